// Round 12
// baseline (144.568 us; speedup 1.0000x reference)
//
#include <hip/hip_runtime.h>
#include <math.h>

#define B_    2
#define LSEQ  1024
#define DM    512
#define DI    1024
#define NS    64
#define TC    64
#define NC    (LSEQ/TC)     // 16
#define LDP   72            // padded stride for corrK tiles only

typedef __bf16 bf16x8 __attribute__((ext_vector_type(8)));
typedef float  f32x4  __attribute__((ext_vector_type(4)));

__device__ __forceinline__ float sp_f(float x)   { return fmaxf(x, 0.f) + log1pf(expf(-fabsf(x))); }
__device__ __forceinline__ float silu_f(float x) { return x / (1.f + expf(-x)); }
__device__ __forceinline__ unsigned short f2bf(float f) {
    unsigned int u = __float_as_uint(f);
    u += 0x7FFF + ((u >> 16) & 1);          // RNE
    return (unsigned short)(u >> 16);
}
__device__ __forceinline__ float bf2f(unsigned short h) {
    return __uint_as_float(((unsigned int)h) << 16);
}
// async global->LDS, 16 B per lane; LDS dest = wave-uniform base + lane*16
__device__ __forceinline__ void gload16(const void* g, void* l) {
    __builtin_amdgcn_global_load_lds(
        (const __attribute__((address_space(1))) unsigned int*)g,
        (__attribute__((address_space(3))) unsigned int*)l, 16, 0, 0);
}

// ---------------------------------------------------------------------------
// All 4 f32->bf16 casts in one launch (3712 blocks exactly).
// ---------------------------------------------------------------------------
__global__ __launch_bounds__(256) void castall(
    const float* __restrict__ x, const float* __restrict__ W_in,
    const float* __restrict__ W_xproj, const float* __restrict__ W_out,
    unsigned short* __restrict__ xb, unsigned short* __restrict__ winb,
    unsigned short* __restrict__ wxb, unsigned short* __restrict__ wob)
{
    int i = (blockIdx.x * 256 + threadIdx.x) * 4;
    const float* s; unsigned short* dst; int off;
    if (i < 1048576)      { s = x;       dst = xb;   off = i; }
    else if (i < 2097152) { s = W_in;    dst = winb; off = i - 1048576; }
    else if (i < 3276800) { s = W_xproj; dst = wxb;  off = i - 2097152; }
    else                  { s = W_out;   dst = wob;  off = i - 3276800; }
    float4 v = *(const float4*)(s + off);
    ushort4 o;
    o.x = f2bf(v.x); o.y = f2bf(v.y); o.z = f2bf(v.z); o.w = f2bf(v.w);
    *(ushort4*)(dst + off) = o;
}

// ---------------------------------------------------------------------------
// bf16 MFMA GEMM: 128x64 tile, BK=64, 4 waves each 32x64.
// R12: STAGE addresses strength-reduced — A-source select hoisted per block
// (every launch keeps each split-K slice within one source), the 6 per-thread
// global pointers precomputed before the K-loop and advanced by 128 B/step.
// Per-step VALU drops ~55 -> ~12 ops (was the binding issue: VALUBusy ~5x
// MfmaUtil in R11 profile). 2-phase dbuf + XOR bank swizzle + XCD swizzle
// retained. mode 0: f32 C. mode 1: bf16 C. mode 2: fused Mamba prep epilogue.
// ---------------------------------------------------------------------------
__global__ __launch_bounds__(256) void gemm128(
    const unsigned short* __restrict__ Alo, const unsigned short* __restrict__ Ahi,
    const unsigned short* __restrict__ B, float* __restrict__ C,
    int M, int N, int K, int wrapK, int ks, int mode,
    const float* __restrict__ A_log, const unsigned short* __restrict__ u_in,
    unsigned* __restrict__ ddu_out,
    unsigned short* __restrict__ Bbf, unsigned short* __restrict__ Cbf)
{
    __shared__ short As0[128 * 64];
    __shared__ short Bs0[64 * 64];
    __shared__ short As1[128 * 64];
    __shared__ short Bs1[64 * 64];
    const int tid  = threadIdx.x;
    const int lane = tid & 63, wid = tid >> 6;

    // XCD-aware swizzle: contiguous work chunk per XCD (grid.x*grid.y % 8 == 0)
    const int gx = gridDim.x;
    int id  = blockIdx.y * gx + blockIdx.x;
    int q   = (gx * gridDim.y) >> 3;
    int swz = (id & 7) * q + (id >> 3);
    const int bm = (swz / gx) * 128, bn = (swz % gx) * 64;

    const int wm = wid * 32;
    const int fr = lane & 15;
    const int h  = fr & 7;                 // read-side bank swizzle
    const int tq = lane >> 4;
    const int Kc = K / ks;
    const int k0beg = blockIdx.z * Kc;
    const int nsteps = Kc / 64;
    float* Cz = C + (size_t)blockIdx.z * M * N;
    unsigned short* Czb = (unsigned short*)C + (size_t)blockIdx.z * M * N;

    // Hoisted A-source resolution (uniform per block: slices never cross wrapK)
    const unsigned short* Asrc;
    int ka0;
    if (k0beg >= wrapK) { Asrc = Ahi; ka0 = k0beg - wrapK; }
    else                { Asrc = Alo; ka0 = k0beg; }

    // Precompute the 6 per-thread global staging pointers (advance 128 B/step)
    const char* pA[4];
    const char* pB[2];
#pragma unroll
    for (int r = 0; r < 4; r++) {
        int o    = tid * 16 + r * 4096;
        int row  = o >> 7;
        int colb = ((((o >> 4) & 7) ^ (row & 7)) << 4);   // pre-swizzled source col
        pA[r] = (const char*)Asrc + ((size_t)(bm + row) * wrapK + ka0) * 2 + colb;
    }
#pragma unroll
    for (int r = 0; r < 2; r++) {
        int o    = tid * 16 + r * 4096;
        int row  = o >> 7;
        int colb = ((((o >> 4) & 7) ^ (row & 7)) << 4);
        pB[r] = (const char*)B + ((size_t)(bn + row) * wrapK + ka0) * 2 + colb;
    }
    const int wbase = wid * 1024;

    f32x4 acc[2][4];
#pragma unroll
    for (int i = 0; i < 2; i++)
#pragma unroll
        for (int j = 0; j < 4; j++) acc[i][j] = (f32x4)0.f;

    auto STAGE = [&](char* Adst, char* Bdst) {
#pragma unroll
        for (int r = 0; r < 4; r++) { gload16(pA[r], Adst + wbase + r * 4096); pA[r] += 128; }
#pragma unroll
        for (int r = 0; r < 2; r++) { gload16(pB[r], Bdst + wbase + r * 4096); pB[r] += 128; }
    };
    auto COMPUTE = [&](const short* Asrc_l, const short* Bsrc_l) {
#pragma unroll
        for (int kk = 0; kk < 2; kk++) {
            const int sc = ((kk * 4 + tq) ^ h) << 3;     // swizzled chunk (shorts)
            bf16x8 af[2], bfr[4];
#pragma unroll
            for (int i = 0; i < 2; i++)
                af[i] = *reinterpret_cast<const bf16x8*>(&Asrc_l[(wm + i * 16 + fr) * 64 + sc]);
#pragma unroll
            for (int j = 0; j < 4; j++)
                bfr[j] = *reinterpret_cast<const bf16x8*>(&Bsrc_l[(j * 16 + fr) * 64 + sc]);
#pragma unroll
            for (int i = 0; i < 2; i++)
#pragma unroll
                for (int j = 0; j < 4; j++)
                    acc[i][j] = __builtin_amdgcn_mfma_f32_16x16x32_bf16(af[i], bfr[j], acc[i][j], 0, 0, 0);
        }
    };

    // 2-phase pipeline, unrolled x2 with distinct buffers
    STAGE((char*)As0, (char*)Bs0);
    __syncthreads();
    for (int st = 0; st < nsteps; st += 2) {
        if (st + 1 < nsteps) STAGE((char*)As1, (char*)Bs1);
        COMPUTE(As0, Bs0);
        __syncthreads();
        if (st + 1 < nsteps) {
            if (st + 2 < nsteps) STAGE((char*)As0, (char*)Bs0);
            COMPUTE(As1, Bs1);
            __syncthreads();
        }
    }

    const int crow = (lane >> 4) * 4;
    if (mode == 2) {
        if (bn < 1024) {                                 // delta region -> packed (dA|du)
#pragma unroll
            for (int j = 0; j < 4; j++) {
                int d = bn + j * 16 + fr;
                float nAd = -expf(A_log[d]);
#pragma unroll
                for (int i = 0; i < 2; i++)
#pragma unroll
                    for (int r = 0; r < 4; r++) {
                        int m = bm + wm + i * 16 + crow + r;
                        float delta = sp_f(acc[i][j][r]);
                        size_t idx = (size_t)m * DI + d;
                        float dA = expf(delta * nAd);
                        float du = delta * bf2f(u_in[idx]);
                        ddu_out[idx] = (unsigned)f2bf(dA) | ((unsigned)f2bf(du) << 16);
                    }
            }
        } else {                                         // B/C pack region
#pragma unroll
            for (int j = 0; j < 4; j++) {
                int cc = bn + j * 16 + fr;
#pragma unroll
                for (int i = 0; i < 2; i++)
#pragma unroll
                    for (int r = 0; r < 4; r++) {
                        int m = bm + wm + i * 16 + crow + r;
                        unsigned short v16 = f2bf(acc[i][j][r]);
                        if (cc < 1024 + NS) Bbf[(size_t)m * NS + cc - 1024]      = v16;
                        else                Cbf[(size_t)m * NS + cc - 1024 - NS] = v16;
                    }
            }
        }
    } else {
#pragma unroll
        for (int i = 0; i < 2; i++)
#pragma unroll
            for (int j = 0; j < 4; j++)
#pragma unroll
                for (int r = 0; r < 4; r++) {
                    size_t idx = (size_t)(bm + wm + i * 16 + crow + r) * N + (bn + j * 16 + fr);
                    if (mode == 1) Czb[idx] = f2bf(acc[i][j][r]);
                    else           Cz[idx]  = acc[i][j][r];
                }
    }
}

// ---------------------------------------------------------------------------
// Split-K reduce: out = p0+p1+p2+p3
// ---------------------------------------------------------------------------
__global__ __launch_bounds__(256) void reduce4(
    const float* __restrict__ p, float* __restrict__ out, int n)
{
    int i = (blockIdx.x * 256 + threadIdx.x) * 4;
    if (i >= n) return;
    float4 a = *(const float4*)(p + i);
    float4 b = *(const float4*)(p + n + i);
    float4 c = *(const float4*)(p + 2 * n + i);
    float4 d = *(const float4*)(p + 3 * n + i);
    float4 o;
    o.x = (a.x + b.x) + (c.x + d.x);
    o.y = (a.y + b.y) + (c.y + d.y);
    o.z = (a.z + b.z) + (c.z + d.z);
    o.w = (a.w + b.w) + (c.w + d.w);
    *(float4*)(out + i) = o;
}

// ---------------------------------------------------------------------------
// Conv (causal fwd + anti-causal bwd) + SiLU -> u; fused D*u and F=0.5*silu(z).
// ---------------------------------------------------------------------------
__global__ __launch_bounds__(256) void convk(
    const unsigned short* __restrict__ xzb, const float* __restrict__ cw,
    const float* __restrict__ cb, const float* __restrict__ Dvec,
    unsigned short* __restrict__ uc2b, unsigned short* __restrict__ ygb,
    unsigned short* __restrict__ Fbuf)
{
    int idx = blockIdx.x * 256 + threadIdx.x;
    int b   = idx >> 20;
    int rem = idx & ((LSEQ * DI) - 1);
    int tau = rem >> 10;
    int d   = rem & (DI - 1);

    const unsigned short* xc = xzb + (size_t)b * LSEQ * (2 * DI);
    float w0 = cw[d * 4 + 0], w1 = cw[d * 4 + 1], w2 = cw[d * 4 + 2], w3 = cw[d * 4 + 3];
    float bias = cb[d];
    float accf = bias, accb = bias;
    {
        int t0 = tau - 3, t1 = tau - 2, t2 = tau - 1;
        if (t0 >= 0) accf = fmaf(w0, bf2f(xc[(size_t)t0 * 2048 + d]), accf);
        if (t1 >= 0) accf = fmaf(w1, bf2f(xc[(size_t)t1 * 2048 + d]), accf);
        if (t2 >= 0) accf = fmaf(w2, bf2f(xc[(size_t)t2 * 2048 + d]), accf);
        accf = fmaf(w3, bf2f(xc[(size_t)tau * 2048 + d]), accf);
    }
    {
        int t0 = tau + 3, t1 = tau + 2, t2 = tau + 1;
        if (t0 < LSEQ) accb = fmaf(w0, bf2f(xc[(size_t)t0 * 2048 + d]), accb);
        if (t1 < LSEQ) accb = fmaf(w1, bf2f(xc[(size_t)t1 * 2048 + d]), accb);
        if (t2 < LSEQ) accb = fmaf(w2, bf2f(xc[(size_t)t2 * 2048 + d]), accb);
        accb = fmaf(w3, bf2f(xc[(size_t)tau * 2048 + d]), accb);
    }
    float uf = silu_f(accf), ub = silu_f(accb);
    size_t fi = ((size_t)b * LSEQ + tau) * DI + d;
    size_t bi = ((size_t)(2 + b) * LSEQ + tau) * DI + d;
    uc2b[fi] = f2bf(uf);
    uc2b[bi] = f2bf(ub);
    float Dd = Dvec[d];
    ygb[fi] = f2bf(Dd * uf);
    ygb[bi] = f2bf(Dd * ub);
    float z = bf2f(xc[(size_t)tau * 2048 + DI + d]);
    Fbuf[fi] = f2bf(0.5f * silu_f(z));
}

// ---------------------------------------------------------------------------
// Pass A: local chunk scan from zero; reads PACKED ddu (dA|du u32) + ygb (Du);
// emits yloc (+Du, into ygb), g (bf16), chunk-end states (bf16), P.
// ---------------------------------------------------------------------------
__global__ __launch_bounds__(256) void passA(
    const unsigned* __restrict__ ddu,
    const unsigned short* __restrict__ Bbf, const unsigned short* __restrict__ Cbf,
    unsigned short* __restrict__ ygb, unsigned short* __restrict__ gbuf,
    unsigned short* __restrict__ sEnd, float* __restrict__ Pbuf)
{
    const int dl   = threadIdx.x >> 2;
    const int nq   = threadIdx.x & 3;
    const int d0   = blockIdx.x * 64;
    const int d    = d0 + dl;
    const int c    = blockIdx.y;
    const int dirb = blockIdx.z;
    const int dir  = dirb >> 1;

    __shared__ float Bsh[TC][NS];
    __shared__ float Csh[TC][NS];
    __shared__ unsigned short gshY[TC][64];
    __shared__ unsigned short gshG[TC][64];

    for (int i = threadIdx.x * 4; i < TC * NS; i += 1024) {
        int tl = i >> 6, n = i & 63;
        int tau = dir ? (LSEQ - 1 - (c * TC + tl)) : (c * TC + tl);
        ushort4 vb = *(const ushort4*)&Bbf[((size_t)dirb * LSEQ + tau) * NS + n];
        ushort4 vc = *(const ushort4*)&Cbf[((size_t)dirb * LSEQ + tau) * NS + n];
        Bsh[tl][n+0] = bf2f(vb.x); Bsh[tl][n+1] = bf2f(vb.y);
        Bsh[tl][n+2] = bf2f(vb.z); Bsh[tl][n+3] = bf2f(vb.w);
        Csh[tl][n+0] = bf2f(vc.x); Csh[tl][n+1] = bf2f(vc.y);
        Csh[tl][n+2] = bf2f(vc.z); Csh[tl][n+3] = bf2f(vc.w);
    }
    __syncthreads();

    float s[16];
#pragma unroll
    for (int i = 0; i < 16; i++) s[i] = 0.f;
    float g_run = 1.f;

    int tau0 = dir ? (LSEQ - 1 - c * TC) : (c * TC);
    long stp = (dir ? -1L : 1L) * (long)DI;
    const unsigned* pW = ddu + ((size_t)dirb * LSEQ + tau0) * DI + d;
    const unsigned short* pY = ygb + ((size_t)dirb * LSEQ + tau0) * DI + d;

    unsigned w = *pW;
    float Du = bf2f(*pY);
    for (int tl = 0; tl < TC; tl++) {
        unsigned w_c = w;
        float Du_c = Du;
        if (tl + 1 < TC) {                        // 1-deep register prefetch
            pW += stp; pY += stp;
            w = *pW; Du = bf2f(*pY);
        }
        float dA_c = bf2f((unsigned short)(w_c & 0xffff));
        float du_c = bf2f((unsigned short)(w_c >> 16));
        g_run *= dA_c;
        float ydot = 0.f;
        const float4* brow = (const float4*)&Bsh[tl][nq * 16];
        const float4* crow = (const float4*)&Csh[tl][nq * 16];
#pragma unroll
        for (int q = 0; q < 4; q++) {
            float4 bv = brow[q];
            float4 cv = crow[q];
            float s0 = fmaf(du_c, bv.x, dA_c * s[4*q+0]); s[4*q+0] = s0; ydot = fmaf(cv.x, s0, ydot);
            float s1 = fmaf(du_c, bv.y, dA_c * s[4*q+1]); s[4*q+1] = s1; ydot = fmaf(cv.y, s1, ydot);
            float s2 = fmaf(du_c, bv.z, dA_c * s[4*q+2]); s[4*q+2] = s2; ydot = fmaf(cv.z, s2, ydot);
            float s3 = fmaf(du_c, bv.w, dA_c * s[4*q+3]); s[4*q+3] = s3; ydot = fmaf(cv.w, s3, ydot);
        }
        ydot += __shfl_xor(ydot, 1);
        ydot += __shfl_xor(ydot, 2);
        if (nq == 0) {
            gshY[tl][dl] = f2bf(Du_c + ydot);
            gshG[tl][dl] = f2bf(g_run);
        }
    }
    __syncthreads();

    size_t base = (((size_t)dirb * NC + c) * DI + d) * NS + nq * 16;
#pragma unroll
    for (int q = 0; q < 4; q++) {
        ushort4 v;
        v.x = f2bf(s[4*q+0]); v.y = f2bf(s[4*q+1]);
        v.z = f2bf(s[4*q+2]); v.w = f2bf(s[4*q+3]);
        *(ushort4*)&sEnd[base + q * 4] = v;
    }
    if (nq == 0) Pbuf[((size_t)dirb * NC + c) * DI + d] = g_run;

    for (int i = threadIdx.x * 4; i < TC * 64; i += 1024) {
        int tl = i >> 6, col = i & 63;
        int tau = dir ? (LSEQ - 1 - (c * TC + tl)) : (c * TC + tl);
        *(ushort4*)&ygb[((size_t)dirb * LSEQ + tau) * DI + d0 + col]  = *(const ushort4*)&gshY[tl][col];
        *(ushort4*)&gbuf[((size_t)dirb * LSEQ + tau) * DI + d0 + col] = *(const ushort4*)&gshG[tl][col];
    }
}

// ---------------------------------------------------------------------------
// Pass B: combine chunk states; sEnd bf16 in, sInitB bf16 out (f32 running).
// ---------------------------------------------------------------------------
__global__ __launch_bounds__(256) void passB(
    const unsigned short* __restrict__ sEnd, const float* __restrict__ Pbuf,
    unsigned short* __restrict__ sInitB)
{
    const int fl   = blockIdx.x * 256 + threadIdx.x;   // d*64 + n
    const int dirb = blockIdx.y;
    const int d    = fl >> 6;
    float run = 0.f;
    for (int c = 0; c < NC; c++) {
        size_t idx = ((size_t)(dirb * NC + c)) * (DI * NS) + fl;
        float tmp = bf2f(sEnd[idx]);
        sInitB[idx] = f2bf(run);
        float P = Pbuf[((size_t)dirb * NC + c) * DI + d];
        run = fmaf(P, run, tmp);
    }
}

// ---------------------------------------------------------------------------
// corrK: per (dirb, chunk, 128-d group): corr = C_chunk[64,64] @ s_init[d,n]^T
// via MFMA (padded LDS: 144-B stride, conflict-free), then
// out = F*(yloc + g*corr) -> ygb in place.
// ---------------------------------------------------------------------------
__global__ __launch_bounds__(256) void corrK(
    const unsigned short* __restrict__ Cbf, const unsigned short* __restrict__ sInitB,
    const unsigned short* __restrict__ gbuf, const unsigned short* __restrict__ Fbuf,
    unsigned short* __restrict__ ygb)
{
    const int tid  = threadIdx.x;
    const int lane = tid & 63, wid = tid >> 6;
    const int d0   = blockIdx.x * 128;
    const int c    = blockIdx.y;
    const int dirb = blockIdx.z;
    const int dir  = dirb >> 1;
    const int b    = dirb & 1;
    const int fr = lane & 15, fk = (lane >> 4) * 8;
    const int wm = (wid >> 1) * 32, wn = (wid & 1) * 64;

    __shared__ short Cs[64 * LDP];
    __shared__ short Ss[128 * LDP];
    __shared__ float corrS[64 * 128];

    for (int i = tid * 4; i < 64 * 64; i += 1024) {
        int tl = i >> 6, n = i & 63;
        int tau = dir ? (LSEQ - 1 - (c * TC + tl)) : (c * TC + tl);
        *(ushort4*)&Cs[tl * LDP + n] = *(const ushort4*)&Cbf[((size_t)dirb * LSEQ + tau) * NS + n];
    }
    for (int i = tid * 4; i < 128 * 64; i += 1024) {
        int r = i >> 6, n = i & 63;
        *(ushort4*)&Ss[r * LDP + n] =
            *(const ushort4*)&sInitB[(((size_t)dirb * NC + c) * DI + d0 + r) * NS + n];
    }
    __syncthreads();

    f32x4 acc[2][4];
#pragma unroll
    for (int i = 0; i < 2; i++)
#pragma unroll
        for (int j = 0; j < 4; j++) acc[i][j] = (f32x4)0.f;

#pragma unroll
    for (int kk = 0; kk < 2; kk++) {
        bf16x8 af[2], bfr[4];
#pragma unroll
        for (int i = 0; i < 2; i++)
            af[i] = *reinterpret_cast<const bf16x8*>(&Cs[(wm + i * 16 + fr) * LDP + kk * 32 + fk]);
#pragma unroll
        for (int j = 0; j < 4; j++)
            bfr[j] = *reinterpret_cast<const bf16x8*>(&Ss[(wn + j * 16 + fr) * LDP + kk * 32 + fk]);
#pragma unroll
        for (int i = 0; i < 2; i++)
#pragma unroll
            for (int j = 0; j < 4; j++)
                acc[i][j] = __builtin_amdgcn_mfma_f32_16x16x32_bf16(af[i], bfr[j], acc[i][j], 0, 0, 0);
    }

    const int crow = (lane >> 4) * 4;
#pragma unroll
    for (int i = 0; i < 2; i++)
#pragma unroll
        for (int j = 0; j < 4; j++)
#pragma unroll
            for (int r = 0; r < 4; r++)
                corrS[(wm + i * 16 + crow + r) * 128 + (wn + j * 16 + fr)] = acc[i][j][r];
    __syncthreads();

    for (int i = tid * 4; i < 64 * 128; i += 1024) {
        int tl = i >> 7, col = i & 127;
        int tau = dir ? (LSEQ - 1 - (c * TC + tl)) : (c * TC + tl);
        size_t gi = ((size_t)dirb * LSEQ + tau) * DI + d0 + col;
        size_t fi = ((size_t)b    * LSEQ + tau) * DI + d0 + col;
        ushort4 g4 = *(const ushort4*)&gbuf[gi];
        ushort4 y4 = *(const ushort4*)&ygb[gi];
        ushort4 F4 = *(const ushort4*)&Fbuf[fi];
        const float* cr = &corrS[tl * 128 + col];
        ushort4 o;
        o.x = f2bf(bf2f(F4.x) * fmaf(bf2f(g4.x), cr[0], bf2f(y4.x)));
        o.y = f2bf(bf2f(F4.y) * fmaf(bf2f(g4.y), cr[1], bf2f(y4.y)));
        o.z = f2bf(bf2f(F4.z) * fmaf(bf2f(g4.z), cr[2], bf2f(y4.z)));
        o.w = f2bf(bf2f(F4.w) * fmaf(bf2f(g4.w), cr[3], bf2f(y4.w)));
        *(ushort4*)&ygb[gi] = o;
    }
}

// ---------------------------------------------------------------------------
extern "C" void kernel_launch(void* const* d_in, const int* in_sizes, int n_in,
                              void* d_out, int out_size, void* d_ws, size_t ws_size,
                              hipStream_t stream)
{
    const float* x      = (const float*)d_in[0];
    const float* W_in   = (const float*)d_in[1];
    const float* conv_w = (const float*)d_in[2];
    const float* conv_b = (const float*)d_in[3];
    const float* W_xprj = (const float*)d_in[4];
    const float* A_log  = (const float*)d_in[5];
    const float* Dvec   = (const float*)d_in[6];
    const float* W_out  = (const float*)d_in[7];
    float* out = (float*)d_out;

    // workspace ~56.5 MB; aliases are dead-before-overwrite (stream order):
    float* ws = (float*)d_ws;
    unsigned*       ddu   = (unsigned*)ws;                        // [4096][1024] u32 (dA|du), 16.8 MB
    unsigned short* uc2b  = (unsigned short*)(ws + 4194304);      // u, 8.4 MB
    unsigned short* xzb   = uc2b + 4194304;                       // 8.4 MB
    unsigned short* ygb   = xzb  + 4194304;                       // Du->yloc->g, 8.4 MB
    unsigned short* gbuf  = ygb  + 4194304;                       // 8.4 MB
    unsigned short* Fbuf  = gbuf + 4194304;                       // 4.2 MB
    unsigned short* Bbf   = Fbuf + 2097152;                       // 0.5 MB
    unsigned short* Cbf   = Bbf  + 262144;                        // 0.5 MB
    unsigned short* wob   = Cbf  + 262144;                        // 1.0 MB
    float*          Pbuf  = (float*)(wob + 524288);               // 0.26 MB
    // aliases:
    unsigned short* xb     = (unsigned short*)ddu;                // dead after gemm1 (ddu written by gemm2)
    unsigned short* winb   = xb + 1048576;                        // dead after gemm1
    unsigned short* wxb    = gbuf;                                // dead after gemm2 (gbuf written in passA)
    unsigned short* sEnd   = xzb;                                 // xzb dead after convk
    unsigned short* sInitB = uc2b;                                // u dead after gemm2 epilogue
    float*          gpart  = (float*)ddu;                         // ddu dead after passA (4x2048x512 f32 = 16.8 MB)

    // 1) bf16 casts
    castall<<<3712, 256, 0, stream>>>(x, W_in, W_xprj, W_out, xb, winb, wxb, wob);

    // 2) xz = x @ W_in^T -> bf16 (M=2048, N=2048, K=512) — 512 blocks
    gemm128<<<dim3(32, 16), 256, 0, stream>>>(xb, nullptr, winb, (float*)xzb,
        B_ * LSEQ, 2 * DI, DM, DM, 1, 1, nullptr, nullptr, nullptr, nullptr, nullptr);

    // 3) conv both dirs + SiLU -> u; fused D*u and F=0.5*silu(z)
    convk<<<(B_ * LSEQ * DI) / 256, 256, 0, stream>>>(xzb, conv_w, conv_b, Dvec, uc2b, ygb, Fbuf);

    // 4) proj GEMM with fused prep epilogue: packed ddu + B,C — 576 blocks
    gemm128<<<dim3(18, 32), 256, 0, stream>>>(uc2b, nullptr, wxb, nullptr,
        4 * LSEQ, DI + 2 * NS, DI, DI, 1, 2, A_log, uc2b, ddu, Bbf, Cbf);

    // 5) pass A: local scans + yloc + g
    passA<<<dim3(16, NC, 4), 256, 0, stream>>>(ddu, Bbf, Cbf, ygb, gbuf, sEnd, Pbuf);

    // 6) pass B: chunk-state combine -> bf16 s_init
    passB<<<dim3(256, 4), 256, 0, stream>>>(sEnd, Pbuf, sInitB);

    // 7) corrK: MFMA correction + epilogue -> final g values in ygb
    corrK<<<dim3(8, NC, 4), 256, 0, stream>>>(Cbf, sInitB, gbuf, Fbuf, ygb);

    // 8) out = [gf | gb] @ [W|W]^T via K-concat (K=2048, wrapK=1024), split-K=4 — 512 blocks
    gemm128<<<dim3(8, 16, 4), 256, 0, stream>>>(ygb, ygb + (size_t)2 * LSEQ * DI, wob, gpart,
        B_ * LSEQ, DM, 2 * DI, DI, 4, 0, nullptr, nullptr, nullptr, nullptr, nullptr);
    reduce4<<<1024, 256, 0, stream>>>(gpart, out, B_ * LSEQ * DM);
}